// Round 8
// baseline (19.961 us; speedup 1.0000x reference)
//
#include <hip/hip_runtime.h>

#define BB 8192
#define SEQF 2560      // floats per sequence (512*5)

typedef float v2f __attribute__((ext_vector_type(2)));

__device__ __forceinline__ float rfl(float x) {
    return __int_as_float(__builtin_amdgcn_readfirstlane(__float_as_int(x)));
}
__device__ __forceinline__ v2f vsplat(float x) { return (v2f){x, x}; }

__device__ __forceinline__ float4 shfl4x1(float4 v) {   // partner (lane^1) copy
    float4 r;
    r.x = __shfl_xor(v.x, 1); r.y = __shfl_xor(v.y, 1);
    r.z = __shfl_xor(v.z, 1); r.w = __shfl_xor(v.w, 1);
    return r;
}
__device__ __forceinline__ float4 sel4(int c, float4 a, float4 b) {  // c ? a : b
    return make_float4(c ? a.x : b.x, c ? a.y : b.y, c ? a.z : b.z, c ? a.w : b.w);
}

// Wave = 2 sequences (lanes 0-31 seq A, 32-63 seq B), lane owns 16 timesteps.
// PAIR-COOPERATIVE LOADS: lanes 2p,2p+1 load their joint 640B chunk interleaved
// 16B so each dwordx4 has both lanes in one 64B line (32 line-reqs/instr, half
// of the 320B-stride pattern). One shfl_xor(1) pass redistributes. Compute,
// tree, renorm identical to R7 (proven).
__global__ __launch_bounds__(128, 3) void crf_fused(const float* __restrict__ feats,
                                                    const float* __restrict__ trans,
                                                    float* __restrict__ out) {
    const int tid  = threadIdx.x;
    const int lane = tid & 63;
    const int half = lane >> 5;      // which sequence of the pair
    const int cpos = lane & 31;      // chunk index within the sequence
    const int b    = lane & 1;       // role within load pair
    const int p    = lane >> 1;      // pair index 0..31 (16 pairs per seq)
    const int wv   = tid >> 6;
    const int s0   = (blockIdx.x * 2 + wv) * 2;

    // ---- pair-interleaved loads: piece k of pair p at f4-index p*40 + 2k + b ----
    const float4* base = (const float4*)(feats + (size_t)s0 * SEQF);
    float4 r0 =base[p*40+ 0+b], r1 =base[p*40+ 2+b], r2 =base[p*40+ 4+b], r3 =base[p*40+ 6+b];
    float4 r4 =base[p*40+ 8+b], r5 =base[p*40+10+b], r6 =base[p*40+12+b], r7 =base[p*40+14+b];
    float4 r8 =base[p*40+16+b], r9 =base[p*40+18+b], r10=base[p*40+20+b], r11=base[p*40+22+b];
    float4 r12=base[p*40+24+b], r13=base[p*40+26+b], r14=base[p*40+28+b], r15=base[p*40+30+b];
    float4 r16=base[p*40+32+b], r17=base[p*40+34+b], r18=base[p*40+36+b], r19=base[p*40+38+b];
    __builtin_amdgcn_sched_barrier(0);   // pin all loads first (max queue depth)

    // ---- uniform transition factors -> SGPRs; bias e^-2 folded in (exact comp later) ----
    const float BIAS = 0.13533528323661270f;   // e^-2
    const float E00=rfl(__expf(trans[0])*BIAS),  E01=rfl(__expf(trans[1])*BIAS),  E02=rfl(__expf(trans[2])*BIAS);
    const float E10=rfl(__expf(trans[5])*BIAS),  E11=rfl(__expf(trans[6])*BIAS),  E12=rfl(__expf(trans[7])*BIAS);
    const float E20=rfl(__expf(trans[10])*BIAS), E21=rfl(__expf(trans[11])*BIAS), E22=rfl(__expf(trans[12])*BIAS);
    const float C0 =rfl(__expf(trans[3])*BIAS),  C1 =rfl(__expf(trans[8])*BIAS),  C2 =rfl(__expf(trans[13])*BIAS);
    const float S0 =rfl(__expf(trans[20])), S1 =rfl(__expf(trans[21])), S2 =rfl(__expf(trans[22]));

    const v2f E00p=vsplat(E00), E01p=vsplat(E01), E02p=vsplat(E02);
    const v2f E10p=vsplat(E10), E11p=vsplat(E11), E12p=vsplat(E12);
    const v2f E20p=vsplat(E20), E21p=vsplat(E21), E22p=vsplat(E22);

    // ---- redistribute: q[j] = this lane's 16-step chunk, float4 slice j ----
    // b=0: q[2i]=r[i],        q[2i+1]=partner r[i]
    // b=1: q[2i]=partner r[10+i], q[2i+1]=r[10+i]
    float4 q[20];
#define REDIST(i, RLO, RHI) do {                        \
        float4 te = shfl4x1(RLO);                       \
        float4 to = shfl4x1(RHI);                       \
        q[2*(i)]   = sel4(b, to, RLO);                  \
        q[2*(i)+1] = sel4(b, RHI, te);                  \
    } while (0)
    REDIST(0, r0, r10); REDIST(1, r1, r11); REDIST(2, r2, r12);
    REDIST(3, r3, r13); REDIST(4, r4, r14); REDIST(5, r5, r15);
    REDIST(6, r6, r16); REDIST(7, r7, r17); REDIST(8, r8, r18);
    REDIST(9, r9, r19);
#undef REDIST

    // first-step factor: chunk 0 of each sequence starts from the START column
    const bool c0 = (cpos == 0);
    const v2f GA0 = c0 ? vsplat(C0) : (v2f){E00, E01};
    const v2f GA1 = c0 ? vsplat(C1) : (v2f){E10, E11};
    const v2f GA2 = c0 ? vsplat(C2) : (v2f){E20, E21};
    const float GB0 = c0 ? C0 : E02;
    const float GB1 = c0 ? C1 : E12;
    const float GB2 = c0 ? C2 : E22;

    // state: MA_i = (M_i0, M_i1) packed; MB_i = M_i2
    v2f MA0, MA1, MA2;
    float MB0, MB1, MB2;
    float ls = 0.0f;

#define CRF_STEP(FA, FB, FC) do {                                   \
        float e0 = __expf(FA), e1 = __expf(FB), e2 = __expf(FC);    \
        v2f NA0 = vsplat(e0) * (E00p*MA0 + E01p*MA1 + E02p*MA2);    \
        v2f NA1 = vsplat(e1) * (E10p*MA0 + E11p*MA1 + E12p*MA2);    \
        v2f NA2 = vsplat(e2) * (E20p*MA0 + E21p*MA1 + E22p*MA2);    \
        float NB0 = e0 * (E00*MB0 + E01*MB1 + E02*MB2);             \
        float NB1 = e1 * (E10*MB0 + E11*MB1 + E12*MB2);             \
        float NB2 = e2 * (E20*MB0 + E21*MB1 + E22*MB2);             \
        MA0=NA0; MA1=NA1; MA2=NA2; MB0=NB0; MB1=NB1; MB2=NB2;       \
    } while (0)

    // exact power-of-two renorm; ls counts the exponent (units of ln2)
#define CRF_RENORM() do {                                           \
        v2f mp = __builtin_elementwise_max(__builtin_elementwise_max(MA0, MA1), MA2); \
        float mm = fmaxf(fmaxf(mp.x, mp.y), fmaxf(fmaxf(MB0, MB1), MB2)); \
        mm = fmaxf(mm, 1e-30f);                                     \
        int ee = (int)((__float_as_uint(mm) >> 23) & 0xffu) - 127;  \
        float sc = __uint_as_float((unsigned)(127 - ee) << 23);     \
        ls += (float)ee;                                            \
        v2f scp = vsplat(sc);                                       \
        MA0*=scp; MA1*=scp; MA2*=scp; MB0*=sc; MB1*=sc; MB2*=sc;    \
    } while (0)

    // suffix-scan level: P = lane+D (later in time); M <- P * M
#define TREE_LEVEL(D, RN) do {                                      \
        v2f PA0, PA1, PA2;                                          \
        PA0.x=__shfl_down(MA0.x,D); PA0.y=__shfl_down(MA0.y,D);     \
        PA1.x=__shfl_down(MA1.x,D); PA1.y=__shfl_down(MA1.y,D);     \
        PA2.x=__shfl_down(MA2.x,D); PA2.y=__shfl_down(MA2.y,D);     \
        float PB0=__shfl_down(MB0,D), PB1=__shfl_down(MB1,D), PB2=__shfl_down(MB2,D); \
        float Pls=__shfl_down(ls, D);                               \
        v2f NA0 = vsplat(PA0.x)*MA0 + vsplat(PA0.y)*MA1 + vsplat(PB0)*MA2; \
        v2f NA1 = vsplat(PA1.x)*MA0 + vsplat(PA1.y)*MA1 + vsplat(PB1)*MA2; \
        v2f NA2 = vsplat(PA2.x)*MA0 + vsplat(PA2.y)*MA1 + vsplat(PB2)*MA2; \
        float NB0 = PA0.x*MB0 + PA0.y*MB1 + PB0*MB2;                \
        float NB1 = PA1.x*MB0 + PA1.y*MB1 + PB1*MB2;                \
        float NB2 = PA2.x*MB0 + PA2.y*MB1 + PB2*MB2;                \
        MA0=NA0; MA1=NA1; MA2=NA2; MB0=NB0; MB1=NB1; MB2=NB2;       \
        ls += Pls;                                                  \
        if (RN) CRF_RENORM();                                       \
    } while (0)

    {   // t0: M = D(e) * G
        float e0 = __expf(q[0].x), e1 = __expf(q[0].y), e2 = __expf(q[0].z);
        MA0 = vsplat(e0) * GA0;  MB0 = e0 * GB0;
        MA1 = vsplat(e1) * GA1;  MB1 = e1 * GB1;
        MA2 = vsplat(e2) * GA2;  MB2 = e2 * GB2;
    }
    CRF_STEP(q[1].y,  q[1].z,  q[1].w);    // t1
    CRF_STEP(q[2].z,  q[2].w,  q[3].x);    // t2
    CRF_STEP(q[3].w,  q[4].x,  q[4].y);    // t3
    CRF_STEP(q[5].x,  q[5].y,  q[5].z);    // t4
    CRF_STEP(q[6].y,  q[6].z,  q[6].w);    // t5
    CRF_STEP(q[7].z,  q[7].w,  q[8].x);    // t6
    CRF_STEP(q[8].w,  q[9].x,  q[9].y);    // t7
    CRF_STEP(q[10].x, q[10].y, q[10].z);   // t8
    CRF_STEP(q[11].y, q[11].z, q[11].w);   // t9
    CRF_STEP(q[12].z, q[12].w, q[13].x);   // t10
    CRF_STEP(q[13].w, q[14].x, q[14].y);   // t11
    CRF_STEP(q[15].x, q[15].y, q[15].z);   // t12
    CRF_STEP(q[16].y, q[16].z, q[16].w);   // t13
    CRF_STEP(q[17].z, q[17].w, q[18].x);   // t14
    CRF_STEP(q[18].w, q[19].x, q[19].y);   // t15
    CRF_RENORM();

    // shared tree: lanes 0-31 compose seq A, lanes 32-63 compose seq B.
    // Cross-boundary shfl pollution only reaches lanes whose results are unread.
    TREE_LEVEL(1, 0);
    TREE_LEVEL(2, 0);
    TREE_LEVEL(4, 1);
    TREE_LEVEL(8, 0);
    TREE_LEVEL(16, 1);

    // lanes 0 and 32: column 0 = full product applied to START-init vector.
    // Bias compensation: 512 biased factors * 2.0 = +1024 (exact).
    float r = S0*MA0.x + S1*MA1.x + S2*MA2.x;
    float res = __logf(r) + ls * 0.69314718055994531f + 1024.0f;
    if (cpos == 0) out[s0 + half] = res;

#undef CRF_STEP
#undef CRF_RENORM
#undef TREE_LEVEL
}

extern "C" void kernel_launch(void* const* d_in, const int* in_sizes, int n_in,
                              void* d_out, int out_size, void* d_ws, size_t ws_size,
                              hipStream_t stream) {
    const float* feats = (const float*)d_in[0];
    const float* trans = (const float*)d_in[1];
    float* out = (float*)d_out;
    (void)d_ws; (void)ws_size;

    crf_fused<<<BB / 4, 128, 0, stream>>>(feats, trans, out);
}